// Round 9
// baseline (414.294 us; speedup 1.0000x reference)
//
#include <hip/hip_runtime.h>

#define NN 50000
#define NE 800000
#define IN_CH 128
#define HID 32
#define HEADS 8
#define HC 256          // HEADS*HID
#define OUT_CH 64
#define NEG_SLOPE 0.2f
#define SCAN_BLOCKS 196  // 196*256 = 50176 >= NN

typedef _Float16 half4 __attribute__((ext_vector_type(4)));
typedef _Float16 half8 __attribute__((ext_vector_type(8)));
typedef float    f32x4 __attribute__((ext_vector_type(4)));

// ---------------- counting sort (CSR by dst) ----------------

__global__ void hist_kernel(const int* __restrict__ dst, int* __restrict__ deg) {
    int e = blockIdx.x * blockDim.x + threadIdx.x;
    if (e < NE) atomicAdd(&deg[dst[e]], 1);
}

__global__ __launch_bounds__(256)
void scan_phase1(const int* __restrict__ deg, int* __restrict__ excl,
                 int* __restrict__ bsum) {
    __shared__ int sm[256];
    const int t = blockIdx.x * 256 + threadIdx.x;
    const int v = (t < NN) ? deg[t] : 0;
    sm[threadIdx.x] = v;
    __syncthreads();
    for (int off = 1; off < 256; off <<= 1) {
        int u = (threadIdx.x >= off) ? sm[threadIdx.x - off] : 0;
        __syncthreads();
        sm[threadIdx.x] += u;
        __syncthreads();
    }
    if (t < NN) excl[t] = sm[threadIdx.x] - v;
    if (threadIdx.x == 255) bsum[blockIdx.x] = sm[255];
}

__global__ __launch_bounds__(256)
void scan_phase2(const int* __restrict__ bsum, int* __restrict__ boff,
                 int* __restrict__ offsets) {
    __shared__ int sm[256];
    const int t = threadIdx.x;
    const int v = (t < SCAN_BLOCKS) ? bsum[t] : 0;
    sm[t] = v;
    __syncthreads();
    for (int off = 1; off < 256; off <<= 1) {
        int u = (t >= off) ? sm[t - off] : 0;
        __syncthreads();
        sm[t] += u;
        __syncthreads();
    }
    if (t < SCAN_BLOCKS) boff[t] = sm[t] - v;
    if (t == 255) offsets[NN] = sm[255];
}

__global__ __launch_bounds__(256)
void scan_phase3(const int* __restrict__ excl, const int* __restrict__ boff,
                 int* __restrict__ offsets, int* __restrict__ cursor) {
    const int t = blockIdx.x * 256 + threadIdx.x;
    if (t < NN) {
        int v = excl[t] + boff[blockIdx.x];
        offsets[t] = v;
        cursor[t]  = v;
    }
}

__global__ void scatter_kernel(const int* __restrict__ src,
                               const int* __restrict__ dst,
                               int* __restrict__ cursor, int* __restrict__ ssrc) {
    int e = blockIdx.x * blockDim.x + threadIdx.x;
    if (e < NE) {
        int d = dst[e];
        int pos = atomicAdd(&cursor[d], 1);
        ssrc[pos] = src[e];
    }
}

// ---------------- fp16 prep ----------------

__global__ void cast_f32_f16(const float* __restrict__ in, _Float16* __restrict__ out,
                             int n8) {
    int i = blockIdx.x * blockDim.x + threadIdx.x;
    if (i >= n8) return;
    float4 a = ((const float4*)in)[i * 2];
    float4 b = ((const float4*)in)[i * 2 + 1];
    half8 h;
    h[0] = (_Float16)a.x; h[1] = (_Float16)a.y; h[2] = (_Float16)a.z; h[3] = (_Float16)a.w;
    h[4] = (_Float16)b.x; h[5] = (_Float16)b.y; h[6] = (_Float16)b.z; h[7] = (_Float16)b.w;
    ((half8*)out)[i] = h;
}

// Wt[n][k] = (fp16) W[k][n]
__global__ void transpose_cast(const float* __restrict__ W, _Float16* __restrict__ Wt,
                               int K, int N) {
    int i = blockIdx.x * blockDim.x + threadIdx.x;
    if (i >= K * N) return;
    int k = i / N, n = i - k * N;
    Wt[(size_t)n * K + k] = (_Float16)W[i];
}

// ---------------- MFMA fp16 GEMM (row-major C) ----------------
__global__ __launch_bounds__(256)
void gemm_mfma_h(const _Float16* __restrict__ A, const _Float16* __restrict__ Bt,
                 _Float16* __restrict__ C, int M, int N, int K) {
    __shared__ _Float16 Asl[64][136];
    __shared__ _Float16 Btl[64][136];
    const int tid  = threadIdx.x;
    const int wave = tid >> 6, lane = tid & 63;
    const int lr = lane & 15, lk = lane >> 4;
    const int bm = blockIdx.x * 64, bn = blockIdx.y * 64;
    const int sr = tid >> 2;
    const int ss = (tid & 3) * 32;

    f32x4 acc[4];
#pragma unroll
    for (int i = 0; i < 4; ++i) acc[i] = (f32x4){0.f, 0.f, 0.f, 0.f};

    for (int k0 = 0; k0 < K; k0 += 128) {
        {
            const int ar = bm + sr;
            half8 v0 = {}, v1 = {}, v2 = {}, v3 = {};
            if (ar < M) {
                const half8* ga = (const half8*)(A + (size_t)ar * K + k0 + ss);
                v0 = ga[0]; v1 = ga[1]; v2 = ga[2]; v3 = ga[3];
            }
            *(half8*)&Asl[sr][ss + 0]  = v0;
            *(half8*)&Asl[sr][ss + 8]  = v1;
            *(half8*)&Asl[sr][ss + 16] = v2;
            *(half8*)&Asl[sr][ss + 24] = v3;
            const half8* gb = (const half8*)(Bt + (size_t)(bn + sr) * K + k0 + ss);
            half8 w0 = gb[0], w1 = gb[1], w2 = gb[2], w3 = gb[3];
            *(half8*)&Btl[sr][ss + 0]  = w0;
            *(half8*)&Btl[sr][ss + 8]  = w1;
            *(half8*)&Btl[sr][ss + 16] = w2;
            *(half8*)&Btl[sr][ss + 24] = w3;
        }
        __syncthreads();
#pragma unroll
        for (int kk = 0; kk < 128; kk += 32) {
            half8 a = *(const half8*)&Asl[wave * 16 + lr][kk + lk * 8];
#pragma unroll
            for (int nt = 0; nt < 4; ++nt) {
                half8 b = *(const half8*)&Btl[nt * 16 + lr][kk + lk * 8];
                acc[nt] = __builtin_amdgcn_mfma_f32_16x16x32_f16(a, b, acc[nt], 0, 0, 0);
            }
        }
        __syncthreads();
    }
#pragma unroll
    for (int nt = 0; nt < 4; ++nt) {
        const int col = bn + nt * 16 + lr;
#pragma unroll
        for (int r = 0; r < 4; ++r) {
            const int m = bm + wave * 16 + lk * 4 + r;
            if (m < M) C[(size_t)m * N + col] = (_Float16)acc[nt][r];
        }
    }
}

// ---------------- MFMA fp16 GEMM (head-major C: [N/32][M][32]) ----------------
__global__ __launch_bounds__(256)
void gemm_mfma_hm(const _Float16* __restrict__ A, const _Float16* __restrict__ Bt,
                  _Float16* __restrict__ C, int M, int N, int K) {
    __shared__ _Float16 Asl[64][136];
    __shared__ _Float16 Btl[64][136];
    const int tid  = threadIdx.x;
    const int wave = tid >> 6, lane = tid & 63;
    const int lr = lane & 15, lk = lane >> 4;
    const int bm = blockIdx.x * 64, bn = blockIdx.y * 64;
    const int sr = tid >> 2;
    const int ss = (tid & 3) * 32;

    f32x4 acc[4];
#pragma unroll
    for (int i = 0; i < 4; ++i) acc[i] = (f32x4){0.f, 0.f, 0.f, 0.f};

    for (int k0 = 0; k0 < K; k0 += 128) {
        {
            const int ar = bm + sr;
            half8 v0 = {}, v1 = {}, v2 = {}, v3 = {};
            if (ar < M) {
                const half8* ga = (const half8*)(A + (size_t)ar * K + k0 + ss);
                v0 = ga[0]; v1 = ga[1]; v2 = ga[2]; v3 = ga[3];
            }
            *(half8*)&Asl[sr][ss + 0]  = v0;
            *(half8*)&Asl[sr][ss + 8]  = v1;
            *(half8*)&Asl[sr][ss + 16] = v2;
            *(half8*)&Asl[sr][ss + 24] = v3;
            const half8* gb = (const half8*)(Bt + (size_t)(bn + sr) * K + k0 + ss);
            half8 w0 = gb[0], w1 = gb[1], w2 = gb[2], w3 = gb[3];
            *(half8*)&Btl[sr][ss + 0]  = w0;
            *(half8*)&Btl[sr][ss + 8]  = w1;
            *(half8*)&Btl[sr][ss + 16] = w2;
            *(half8*)&Btl[sr][ss + 24] = w3;
        }
        __syncthreads();
#pragma unroll
        for (int kk = 0; kk < 128; kk += 32) {
            half8 a = *(const half8*)&Asl[wave * 16 + lr][kk + lk * 8];
#pragma unroll
            for (int nt = 0; nt < 4; ++nt) {
                half8 b = *(const half8*)&Btl[nt * 16 + lr][kk + lk * 8];
                acc[nt] = __builtin_amdgcn_mfma_f32_16x16x32_f16(a, b, acc[nt], 0, 0, 0);
            }
        }
        __syncthreads();
    }
    // head-major store: col -> (head = col>>5, c = col&31)
#pragma unroll
    for (int nt = 0; nt < 4; ++nt) {
        const int col = bn + nt * 16 + lr;
        const int hh = col >> 5, cc = col & 31;
#pragma unroll
        for (int r = 0; r < 4; ++r) {
            const int m = bm + wave * 16 + lk * 4 + r;
            if (m < M) C[((size_t)hh * M + m) * 32 + cc] = (_Float16)acc[nt][r];
        }
    }
}

// ---------------- attention coefficients ----------------

// layer 1, head-major: thread handles (n, h=blockIdx.y); coalesced 64B rows.
__global__ void attcoef1(const _Float16* __restrict__ xsh, const float* __restrict__ att_s,
                         const float* __restrict__ att_d,
                         float* __restrict__ a_sh, float* __restrict__ a_dh) {
    int n = blockIdx.x * blockDim.x + threadIdx.x;
    int h = blockIdx.y;
    if (n >= NN) return;
    const _Float16* xp = xsh + ((size_t)h * NN + n) * 32;
    const float* sp = att_s + h * 32;
    const float* dp = att_d + h * 32;
    float as = 0.f, ad = 0.f;
#pragma unroll
    for (int i = 0; i < 4; ++i) {
        half8 v = *(const half8*)(xp + i * 8);
#pragma unroll
        for (int j = 0; j < 8; ++j) {
            float f = (float)v[j];
            as += f * sp[i * 8 + j];
            ad += f * dp[i * 8 + j];
        }
    }
    a_sh[(size_t)h * NN + n] = as;
    a_dh[(size_t)h * NN + n] = ad;
}

__global__ void attcoef2(const _Float16* __restrict__ xs, const float* __restrict__ att_s,
                         const float* __restrict__ att_d,
                         float* __restrict__ a_s, float* __restrict__ a_d) {
    int n = blockIdx.x * blockDim.x + threadIdx.x;
    if (n >= NN) return;
    const _Float16* xp = xs + (long)n * 64;
    float as = 0.f, ad = 0.f;
#pragma unroll
    for (int i = 0; i < 8; ++i) {
        half8 v = *(const half8*)(xp + i * 8);
#pragma unroll
        for (int j = 0; j < 8; ++j) {
            float f = (float)v[j];
            as += f * att_s[i * 8 + j];
            ad += f * att_d[i * 8 + j];
        }
    }
    a_s[n] = as;
    a_d[n] = ad;
}

// ---------------- aggregation ----------------

__device__ __forceinline__ float lrelu(float x) { return x > 0.f ? x : NEG_SLOPE * x; }

// layer 1, per-(node,head) waves with head<->XCD affinity (head = blockIdx&7:
// consecutive blocks round-robin XCDs, so each XCD touches only its head's
// 3.2MB table -> L2-resident; correctness does not depend on the mapping).
// Wave: 8 edges in flight x 8 lanes/edge (half4 = 8B/lane, 64B line/edge).
// Scores for 64-edge chunks precomputed in regs, distributed via shfl.
__global__ __launch_bounds__(256)
void agg1(const _Float16* __restrict__ xsh,   // [8][NN][32]
          const float* __restrict__ a_sh,     // [8][NN]
          const float* __restrict__ a_dh,     // [8][NN]
          const int* __restrict__ offsets, const int* __restrict__ ssrc,
          const float* __restrict__ bias,
          _Float16* __restrict__ out) {       // [NN][256]
    const int b = blockIdx.x;
    const int head = b & 7;
    const int wave = threadIdx.x >> 6;
    const int lane = threadIdx.x & 63;
    const int n = (b >> 3) * 4 + wave;
    if (n >= NN) return;
    const int eslot = lane >> 3;
    const int ch = (lane & 7) * 4;
    const _Float16* xh = xsh + (size_t)head * NN * 32;
    const float* ash = a_sh + (size_t)head * NN;

    const float adn = a_dh[(size_t)head * NN + n];
    const int beg = offsets[n], end = offsets[n + 1];

    float den = 0.f, ax = 0.f, ay = 0.f, az = 0.f, aw = 0.f;

    for (int base = beg; base < end; base += 64) {
        const int cnt = min(64, end - base);
        int sidx = 0;
        float pe = 0.f;
        if (lane < cnt) {
            sidx = ssrc[base + lane];
            pe = __expf(lrelu(ash[sidx] + adn));
        }
        for (int u = 0; u * 8 < cnt; ++u) {
            int   es = __shfl(sidx, u * 8 + eslot);
            float p  = __shfl(pe,   u * 8 + eslot);   // p==0 for padded slots
            half4 v  = *(const half4*)(xh + (size_t)es * 32 + ch);
            den += p;
            ax += p * (float)v[0]; ay += p * (float)v[1];
            az += p * (float)v[2]; aw += p * (float)v[3];
        }
    }
    // reduce across the 8 edge-slots (lane bits 3..5); channels preserved.
#pragma unroll
    for (int m = 8; m <= 32; m <<= 1) {
        den += __shfl_xor(den, m);
        ax  += __shfl_xor(ax, m);
        ay  += __shfl_xor(ay, m);
        az  += __shfl_xor(az, m);
        aw  += __shfl_xor(aw, m);
    }
    // self loop (uniform across lanes after reduction)
    const float pself = __expf(lrelu(ash[n] + adn));
    half4 sv = *(const half4*)(xh + (size_t)n * 32 + ch);
    den += pself;
    ax += pself * (float)sv[0]; ay += pself * (float)sv[1];
    az += pself * (float)sv[2]; aw += pself * (float)sv[3];

    if (eslot == 0) {
        const float inv = 1.0f / den;
        float4 bb = *(const float4*)(bias + head * 32 + ch);
        float ox = ax * inv + bb.x, oy = ay * inv + bb.y;
        float oz = az * inv + bb.z, ow = aw * inv + bb.w;
        ox = ox > 0.f ? ox : expm1f(ox);
        oy = oy > 0.f ? oy : expm1f(oy);
        oz = oz > 0.f ? oz : expm1f(oz);
        ow = ow > 0.f ? ow : expm1f(ow);
        half4 ho;
        ho[0] = (_Float16)ox; ho[1] = (_Float16)oy;
        ho[2] = (_Float16)oz; ho[3] = (_Float16)ow;
        *(half4*)(out + (size_t)n * HC + head * 32 + ch) = ho;
    }
}

// layer 2: H=1, C=64; scores via shfl; fp16 rows of 128B; f32 output.
__global__ __launch_bounds__(256)
void agg2(const _Float16* __restrict__ xs, const float* __restrict__ a_s,
          const float* __restrict__ a_d, const int* __restrict__ offsets,
          const int* __restrict__ ssrc, const float* __restrict__ bias,
          float* __restrict__ out) {
    const int wave = (blockIdx.x * blockDim.x + threadIdx.x) >> 6;
    const int lane = threadIdx.x & 63;
    if (wave >= NN) return;
    const int n = wave;

    const float adn = a_d[n];
    const int beg = offsets[n], end = offsets[n + 1];

    float pself = __expf(lrelu(a_s[n] + adn));
    float den = pself;
    float acc = pself * (float)xs[(long)n * OUT_CH + lane];

    for (int base = beg; base < end; base += 64) {
        const int cnt = min(64, end - base);
        int sidx = 0;
        float pe = 0.f;
        if (lane < cnt) {
            sidx = ssrc[base + lane];
            pe = __expf(lrelu(a_s[sidx] + adn));
        }
        int u = 0;
        for (; u + 8 <= cnt; u += 8) {
            int s0 = __shfl(sidx, u + 0), s1 = __shfl(sidx, u + 1);
            int s2 = __shfl(sidx, u + 2), s3 = __shfl(sidx, u + 3);
            int s4 = __shfl(sidx, u + 4), s5 = __shfl(sidx, u + 5);
            int s6 = __shfl(sidx, u + 6), s7 = __shfl(sidx, u + 7);
            float p0 = __shfl(pe, u + 0), p1 = __shfl(pe, u + 1);
            float p2 = __shfl(pe, u + 2), p3 = __shfl(pe, u + 3);
            float p4 = __shfl(pe, u + 4), p5 = __shfl(pe, u + 5);
            float p6 = __shfl(pe, u + 6), p7 = __shfl(pe, u + 7);
            float v0 = (float)xs[(long)s0 * OUT_CH + lane];
            float v1 = (float)xs[(long)s1 * OUT_CH + lane];
            float v2 = (float)xs[(long)s2 * OUT_CH + lane];
            float v3 = (float)xs[(long)s3 * OUT_CH + lane];
            float v4 = (float)xs[(long)s4 * OUT_CH + lane];
            float v5 = (float)xs[(long)s5 * OUT_CH + lane];
            float v6 = (float)xs[(long)s6 * OUT_CH + lane];
            float v7 = (float)xs[(long)s7 * OUT_CH + lane];
            den += ((p0 + p1) + (p2 + p3)) + ((p4 + p5) + (p6 + p7));
            acc += p0 * v0 + p1 * v1 + p2 * v2 + p3 * v3
                 + p4 * v4 + p5 * v5 + p6 * v6 + p7 * v7;
        }
        for (; u < cnt; ++u) {
            int s = __shfl(sidx, u);
            float p = __shfl(pe, u);
            den += p;
            acc += p * (float)xs[(long)s * OUT_CH + lane];
        }
    }
    out[(long)n * OUT_CH + lane] = acc / den + bias[lane];
}

// ---------------- launch ----------------

extern "C" void kernel_launch(void* const* d_in, const int* in_sizes, int n_in,
                              void* d_out, int out_size, void* d_ws, size_t ws_size,
                              hipStream_t stream) {
    const float* x     = (const float*)d_in[0];
    const int*   ei    = (const int*)d_in[1];      // int32 edge index [2, E]
    const float* W1    = (const float*)d_in[2];
    const float* atts1 = (const float*)d_in[3];
    const float* attd1 = (const float*)d_in[4];
    const float* bias1 = (const float*)d_in[5];
    const float* W2    = (const float*)d_in[6];
    const float* atts2 = (const float*)d_in[7];
    const float* attd2 = (const float*)d_in[8];
    const float* bias2 = (const float*)d_in[9];
    float*       out   = (float*)d_out;

    const int* srcp = ei;
    const int* dstp = ei + NE;

    char* ws = (char*)d_ws;
    size_t off = 0;
    auto alloc = [&](size_t bytes) -> void* {
        void* p = ws + off;
        off += (bytes + 255) & ~(size_t)255;
        return p;
    };
    _Float16* xh    = (_Float16*)alloc((size_t)NN * IN_CH * 2);  // 12.8 MB
    _Float16* xsh1  = (_Float16*)alloc((size_t)NN * HC * 2);     // 25.6 MB head-major
    _Float16* h1h   = (_Float16*)alloc((size_t)NN * HC * 2);     // 25.6 MB row-major
    _Float16* W1t   = (_Float16*)alloc((size_t)HC * IN_CH * 2);
    _Float16* W2t   = (_Float16*)alloc((size_t)OUT_CH * HC * 2);
    float*    as1   = (float*)alloc((size_t)NN * HEADS * 4);     // head-major [8][NN]
    float*    ad1   = (float*)alloc((size_t)NN * HEADS * 4);
    int*   deg      = (int*)alloc((size_t)NN * 4);
    int*   offsets  = (int*)alloc((size_t)(NN + 1) * 4);
    int*   cursor   = (int*)alloc((size_t)NN * 4);
    int*   ssrc     = (int*)alloc((size_t)NE * 4);
    int*   excl     = (int*)alloc((size_t)NN * 4);
    int*   bsum     = (int*)alloc((size_t)SCAN_BLOCKS * 4);
    int*   boff     = (int*)alloc((size_t)SCAN_BLOCKS * 4);
    // layer-2 scratch aliases layer-1 buffers dead after agg1:
    _Float16* xs2h = xsh1;
    float*    as2  = as1;
    float*    ad2  = ad1;

    // --- CSR build ---
    hipMemsetAsync(deg, 0, (size_t)NN * 4, stream);
    hist_kernel<<<(NE + 255) / 256, 256, 0, stream>>>(dstp, deg);
    scan_phase1<<<SCAN_BLOCKS, 256, 0, stream>>>(deg, excl, bsum);
    scan_phase2<<<1, 256, 0, stream>>>(bsum, boff, offsets);
    scan_phase3<<<SCAN_BLOCKS, 256, 0, stream>>>(excl, boff, offsets, cursor);
    scatter_kernel<<<(NE + 255) / 256, 256, 0, stream>>>(srcp, dstp, cursor, ssrc);

    // --- fp16 prep ---
    cast_f32_f16<<<(NN * IN_CH / 8 + 255) / 256, 256, 0, stream>>>(x, xh, NN * IN_CH / 8);
    transpose_cast<<<(IN_CH * HC + 255) / 256, 256, 0, stream>>>(W1, W1t, IN_CH, HC);
    transpose_cast<<<(HC * OUT_CH + 255) / 256, 256, 0, stream>>>(W2, W2t, HC, OUT_CH);

    // --- layer 1 ---
    {
        dim3 grid((NN + 63) / 64, HC / 64);
        gemm_mfma_hm<<<grid, 256, 0, stream>>>(xh, W1t, xsh1, NN, HC, IN_CH);
    }
    {
        dim3 grid((NN + 255) / 256, HEADS);
        attcoef1<<<grid, 256, 0, stream>>>(xsh1, atts1, attd1, as1, ad1);
    }
    agg1<<<((NN + 3) / 4) * 8, 256, 0, stream>>>(xsh1, as1, ad1, offsets, ssrc, bias1, h1h);

    // --- layer 2 ---
    {
        dim3 grid((NN + 63) / 64, OUT_CH / 64);
        gemm_mfma_h<<<grid, 256, 0, stream>>>(h1h, W2t, xs2h, NN, OUT_CH, HC);
    }
    attcoef2<<<(NN + 255) / 256, 256, 0, stream>>>(xs2h, atts2, attd2, as2, ad2);
    agg2<<<(NN + 3) / 4, 256, 0, stream>>>(xs2h, as2, ad2, offsets, ssrc, bias2, out);
}

// Round 10
// 325.973 us; speedup vs baseline: 1.2709x; 1.2709x over previous
//
#include <hip/hip_runtime.h>

#define NN 50000
#define NE 800000
#define IN_CH 128
#define HID 32
#define HEADS 8
#define HC 256          // HEADS*HID
#define OUT_CH 64
#define NEG_SLOPE 0.2f
#define SCAN_BLOCKS 196  // 196*256 = 50176 >= NN

typedef _Float16 half4 __attribute__((ext_vector_type(4)));
typedef _Float16 half8 __attribute__((ext_vector_type(8)));
typedef float    f32x4 __attribute__((ext_vector_type(4)));

// ---------------- counting sort (CSR by dst) ----------------

__global__ void hist_kernel(const int* __restrict__ dst, int* __restrict__ deg) {
    int e = blockIdx.x * blockDim.x + threadIdx.x;
    if (e < NE) atomicAdd(&deg[dst[e]], 1);
}

__global__ __launch_bounds__(256)
void scan_phase1(const int* __restrict__ deg, int* __restrict__ excl,
                 int* __restrict__ bsum) {
    __shared__ int sm[256];
    const int t = blockIdx.x * 256 + threadIdx.x;
    const int v = (t < NN) ? deg[t] : 0;
    sm[threadIdx.x] = v;
    __syncthreads();
    for (int off = 1; off < 256; off <<= 1) {
        int u = (threadIdx.x >= off) ? sm[threadIdx.x - off] : 0;
        __syncthreads();
        sm[threadIdx.x] += u;
        __syncthreads();
    }
    if (t < NN) excl[t] = sm[threadIdx.x] - v;
    if (threadIdx.x == 255) bsum[blockIdx.x] = sm[255];
}

__global__ __launch_bounds__(256)
void scan_phase2(const int* __restrict__ bsum, int* __restrict__ boff,
                 int* __restrict__ offsets) {
    __shared__ int sm[256];
    const int t = threadIdx.x;
    const int v = (t < SCAN_BLOCKS) ? bsum[t] : 0;
    sm[t] = v;
    __syncthreads();
    for (int off = 1; off < 256; off <<= 1) {
        int u = (t >= off) ? sm[t - off] : 0;
        __syncthreads();
        sm[t] += u;
        __syncthreads();
    }
    if (t < SCAN_BLOCKS) boff[t] = sm[t] - v;
    if (t == 255) offsets[NN] = sm[255];
}

__global__ __launch_bounds__(256)
void scan_phase3(const int* __restrict__ excl, const int* __restrict__ boff,
                 int* __restrict__ offsets, int* __restrict__ cursor) {
    const int t = blockIdx.x * 256 + threadIdx.x;
    if (t < NN) {
        int v = excl[t] + boff[blockIdx.x];
        offsets[t] = v;
        cursor[t]  = v;
    }
}

__global__ void scatter_kernel(const int* __restrict__ src,
                               const int* __restrict__ dst,
                               int* __restrict__ cursor, int* __restrict__ ssrc) {
    int e = blockIdx.x * blockDim.x + threadIdx.x;
    if (e < NE) {
        int d = dst[e];
        int pos = atomicAdd(&cursor[d], 1);
        ssrc[pos] = src[e];
    }
}

// ---------------- fp16 prep ----------------

__global__ void cast_f32_f16(const float* __restrict__ in, _Float16* __restrict__ out,
                             int n8) {
    int i = blockIdx.x * blockDim.x + threadIdx.x;
    if (i >= n8) return;
    float4 a = ((const float4*)in)[i * 2];
    float4 b = ((const float4*)in)[i * 2 + 1];
    half8 h;
    h[0] = (_Float16)a.x; h[1] = (_Float16)a.y; h[2] = (_Float16)a.z; h[3] = (_Float16)a.w;
    h[4] = (_Float16)b.x; h[5] = (_Float16)b.y; h[6] = (_Float16)b.z; h[7] = (_Float16)b.w;
    ((half8*)out)[i] = h;
}

// Wt[n][k] = (fp16) W[k][n]
__global__ void transpose_cast(const float* __restrict__ W, _Float16* __restrict__ Wt,
                               int K, int N) {
    int i = blockIdx.x * blockDim.x + threadIdx.x;
    if (i >= K * N) return;
    int k = i / N, n = i - k * N;
    Wt[(size_t)n * K + k] = (_Float16)W[i];
}

// ---------------- MFMA fp16 GEMM (row-major C) ----------------
__global__ __launch_bounds__(256)
void gemm_mfma_h(const _Float16* __restrict__ A, const _Float16* __restrict__ Bt,
                 _Float16* __restrict__ C, int M, int N, int K) {
    __shared__ _Float16 Asl[64][136];
    __shared__ _Float16 Btl[64][136];
    const int tid  = threadIdx.x;
    const int wave = tid >> 6, lane = tid & 63;
    const int lr = lane & 15, lk = lane >> 4;
    const int bm = blockIdx.x * 64, bn = blockIdx.y * 64;
    const int sr = tid >> 2;
    const int ss = (tid & 3) * 32;

    f32x4 acc[4];
#pragma unroll
    for (int i = 0; i < 4; ++i) acc[i] = (f32x4){0.f, 0.f, 0.f, 0.f};

    for (int k0 = 0; k0 < K; k0 += 128) {
        {
            const int ar = bm + sr;
            half8 v0 = {}, v1 = {}, v2 = {}, v3 = {};
            if (ar < M) {
                const half8* ga = (const half8*)(A + (size_t)ar * K + k0 + ss);
                v0 = ga[0]; v1 = ga[1]; v2 = ga[2]; v3 = ga[3];
            }
            *(half8*)&Asl[sr][ss + 0]  = v0;
            *(half8*)&Asl[sr][ss + 8]  = v1;
            *(half8*)&Asl[sr][ss + 16] = v2;
            *(half8*)&Asl[sr][ss + 24] = v3;
            const half8* gb = (const half8*)(Bt + (size_t)(bn + sr) * K + k0 + ss);
            half8 w0 = gb[0], w1 = gb[1], w2 = gb[2], w3 = gb[3];
            *(half8*)&Btl[sr][ss + 0]  = w0;
            *(half8*)&Btl[sr][ss + 8]  = w1;
            *(half8*)&Btl[sr][ss + 16] = w2;
            *(half8*)&Btl[sr][ss + 24] = w3;
        }
        __syncthreads();
#pragma unroll
        for (int kk = 0; kk < 128; kk += 32) {
            half8 a = *(const half8*)&Asl[wave * 16 + lr][kk + lk * 8];
#pragma unroll
            for (int nt = 0; nt < 4; ++nt) {
                half8 b = *(const half8*)&Btl[nt * 16 + lr][kk + lk * 8];
                acc[nt] = __builtin_amdgcn_mfma_f32_16x16x32_f16(a, b, acc[nt], 0, 0, 0);
            }
        }
        __syncthreads();
    }
#pragma unroll
    for (int nt = 0; nt < 4; ++nt) {
        const int col = bn + nt * 16 + lr;
#pragma unroll
        for (int r = 0; r < 4; ++r) {
            const int m = bm + wave * 16 + lk * 4 + r;
            if (m < M) C[(size_t)m * N + col] = (_Float16)acc[nt][r];
        }
    }
}

// ---------------- MFMA fp16 GEMM (head-major C: [N/32][M][32]) ----------------
__global__ __launch_bounds__(256)
void gemm_mfma_hm(const _Float16* __restrict__ A, const _Float16* __restrict__ Bt,
                  _Float16* __restrict__ C, int M, int N, int K) {
    __shared__ _Float16 Asl[64][136];
    __shared__ _Float16 Btl[64][136];
    const int tid  = threadIdx.x;
    const int wave = tid >> 6, lane = tid & 63;
    const int lr = lane & 15, lk = lane >> 4;
    const int bm = blockIdx.x * 64, bn = blockIdx.y * 64;
    const int sr = tid >> 2;
    const int ss = (tid & 3) * 32;

    f32x4 acc[4];
#pragma unroll
    for (int i = 0; i < 4; ++i) acc[i] = (f32x4){0.f, 0.f, 0.f, 0.f};

    for (int k0 = 0; k0 < K; k0 += 128) {
        {
            const int ar = bm + sr;
            half8 v0 = {}, v1 = {}, v2 = {}, v3 = {};
            if (ar < M) {
                const half8* ga = (const half8*)(A + (size_t)ar * K + k0 + ss);
                v0 = ga[0]; v1 = ga[1]; v2 = ga[2]; v3 = ga[3];
            }
            *(half8*)&Asl[sr][ss + 0]  = v0;
            *(half8*)&Asl[sr][ss + 8]  = v1;
            *(half8*)&Asl[sr][ss + 16] = v2;
            *(half8*)&Asl[sr][ss + 24] = v3;
            const half8* gb = (const half8*)(Bt + (size_t)(bn + sr) * K + k0 + ss);
            half8 w0 = gb[0], w1 = gb[1], w2 = gb[2], w3 = gb[3];
            *(half8*)&Btl[sr][ss + 0]  = w0;
            *(half8*)&Btl[sr][ss + 8]  = w1;
            *(half8*)&Btl[sr][ss + 16] = w2;
            *(half8*)&Btl[sr][ss + 24] = w3;
        }
        __syncthreads();
#pragma unroll
        for (int kk = 0; kk < 128; kk += 32) {
            half8 a = *(const half8*)&Asl[wave * 16 + lr][kk + lk * 8];
#pragma unroll
            for (int nt = 0; nt < 4; ++nt) {
                half8 b = *(const half8*)&Btl[nt * 16 + lr][kk + lk * 8];
                acc[nt] = __builtin_amdgcn_mfma_f32_16x16x32_f16(a, b, acc[nt], 0, 0, 0);
            }
        }
        __syncthreads();
    }
    // head-major store: col -> (head = col>>5, c = col&31)
#pragma unroll
    for (int nt = 0; nt < 4; ++nt) {
        const int col = bn + nt * 16 + lr;
        const int hh = col >> 5, cc = col & 31;
#pragma unroll
        for (int r = 0; r < 4; ++r) {
            const int m = bm + wave * 16 + lk * 4 + r;
            if (m < M) C[((size_t)hh * M + m) * 32 + cc] = (_Float16)acc[nt][r];
        }
    }
}

// ---------------- attention coefficients ----------------

__global__ void attcoef1(const _Float16* __restrict__ xsh, const float* __restrict__ att_s,
                         const float* __restrict__ att_d,
                         float* __restrict__ a_sh, float* __restrict__ a_dh) {
    int n = blockIdx.x * blockDim.x + threadIdx.x;
    int h = blockIdx.y;
    if (n >= NN) return;
    const _Float16* xp = xsh + ((size_t)h * NN + n) * 32;
    const float* sp = att_s + h * 32;
    const float* dp = att_d + h * 32;
    float as = 0.f, ad = 0.f;
#pragma unroll
    for (int i = 0; i < 4; ++i) {
        half8 v = *(const half8*)(xp + i * 8);
#pragma unroll
        for (int j = 0; j < 8; ++j) {
            float f = (float)v[j];
            as += f * sp[i * 8 + j];
            ad += f * dp[i * 8 + j];
        }
    }
    a_sh[(size_t)h * NN + n] = as;
    a_dh[(size_t)h * NN + n] = ad;
}

__global__ void attcoef2(const _Float16* __restrict__ xs, const float* __restrict__ att_s,
                         const float* __restrict__ att_d,
                         float* __restrict__ a_s, float* __restrict__ a_d) {
    int n = blockIdx.x * blockDim.x + threadIdx.x;
    if (n >= NN) return;
    const _Float16* xp = xs + (long)n * 64;
    float as = 0.f, ad = 0.f;
#pragma unroll
    for (int i = 0; i < 8; ++i) {
        half8 v = *(const half8*)(xp + i * 8);
#pragma unroll
        for (int j = 0; j < 8; ++j) {
            float f = (float)v[j];
            as += f * att_s[i * 8 + j];
            ad += f * att_d[i * 8 + j];
        }
    }
    a_s[n] = as;
    a_d[n] = ad;
}

// ---------------- aggregation ----------------

__device__ __forceinline__ float lrelu(float x) { return x > 0.f ? x : NEG_SLOPE * x; }

// layer 1: wave = (head, 8 node-slots x 8 lanes). head = blockIdx&7 keeps the
// per-head 3.2MB table XCD/L2-resident (round-9-verified: FETCH 221->45MB).
// Slot processes its node's edges 2 at a time; score exp is computed
// redundantly across the slot's 8 lanes (free, same wave). No shfl, no LDS,
// no reduce epilogue -> ~2 wave-inst/edge (round 9 was ~9, VALU-saturated).
__global__ __launch_bounds__(256)
void agg1(const _Float16* __restrict__ xsh,   // [8][NN][32]
          const float* __restrict__ a_sh,     // [8][NN]
          const float* __restrict__ a_dh,     // [8][NN]
          const int* __restrict__ offsets, const int* __restrict__ ssrc,
          const float* __restrict__ bias,
          _Float16* __restrict__ out) {       // [NN][256]
    const int head = blockIdx.x & 7;
    const int grp  = blockIdx.x >> 3;
    const int wave = threadIdx.x >> 6;
    const int lane = threadIdx.x & 63;
    const int slot = lane >> 3;
    const int j4   = (lane & 7) * 4;
    const int n    = grp * 32 + wave * 8 + slot;
    const bool valid = (n < NN);
    const _Float16* xh = xsh + (size_t)head * NN * 32;
    const float* ash = a_sh + (size_t)head * NN;

    int beg = 0, end = 0;
    float adn = 0.f;
    if (valid) {
        beg = offsets[n];
        end = offsets[n + 1];
        adn = a_dh[(size_t)head * NN + n];
    }
    float den = 0.f, c0 = 0.f, c1 = 0.f, c2 = 0.f, c3 = 0.f;
    int e = beg;
    while (__ballot(e < end) != 0ull) {
        const bool a0 = e < end, a1 = (e + 1) < end;
        const int i0 = a0 ? e : 0, i1 = a1 ? (e + 1) : 0;
        const int s0 = ssrc[i0], s1 = ssrc[i1];
        const float sc0 = ash[s0], sc1 = ash[s1];
        half4 v0 = *(const half4*)(xh + (size_t)s0 * 32 + j4);
        half4 v1 = *(const half4*)(xh + (size_t)s1 * 32 + j4);
        const float p0 = a0 ? __expf(lrelu(sc0 + adn)) : 0.f;
        const float p1 = a1 ? __expf(lrelu(sc1 + adn)) : 0.f;
        den += p0 + p1;
        c0 += p0 * (float)v0[0] + p1 * (float)v1[0];
        c1 += p0 * (float)v0[1] + p1 * (float)v1[1];
        c2 += p0 * (float)v0[2] + p1 * (float)v1[2];
        c3 += p0 * (float)v0[3] + p1 * (float)v1[3];
        e += 2;
    }
    if (valid) {
        const float ps = __expf(lrelu(ash[n] + adn));
        half4 sv = *(const half4*)(xh + (size_t)n * 32 + j4);
        den += ps;
        c0 += ps * (float)sv[0]; c1 += ps * (float)sv[1];
        c2 += ps * (float)sv[2]; c3 += ps * (float)sv[3];
        const float inv = 1.0f / den;
        float4 bb = *(const float4*)(bias + head * 32 + j4);
        float o0 = c0 * inv + bb.x, o1 = c1 * inv + bb.y;
        float o2 = c2 * inv + bb.z, o3 = c3 * inv + bb.w;
        o0 = o0 > 0.f ? o0 : expm1f(o0);
        o1 = o1 > 0.f ? o1 : expm1f(o1);
        o2 = o2 > 0.f ? o2 : expm1f(o2);
        o3 = o3 > 0.f ? o3 : expm1f(o3);
        half4 ho;
        ho[0] = (_Float16)o0; ho[1] = (_Float16)o1;
        ho[2] = (_Float16)o2; ho[3] = (_Float16)o3;
        *(half4*)(out + (size_t)n * HC + head * 32 + j4) = ho;
    }
}

// layer 2: same slot structure, H=1, C=64: 8 lanes x half8 = 128B row.
__global__ __launch_bounds__(256)
void agg2(const _Float16* __restrict__ xs,    // [NN][64]
          const float* __restrict__ a_s, const float* __restrict__ a_d,
          const int* __restrict__ offsets, const int* __restrict__ ssrc,
          const float* __restrict__ bias,
          float* __restrict__ out) {          // [NN][64]
    const int grp  = blockIdx.x;
    const int wave = threadIdx.x >> 6;
    const int lane = threadIdx.x & 63;
    const int slot = lane >> 3;
    const int j8   = (lane & 7) * 8;
    const int n    = grp * 32 + wave * 8 + slot;
    const bool valid = (n < NN);

    int beg = 0, end = 0;
    float adn = 0.f;
    if (valid) {
        beg = offsets[n];
        end = offsets[n + 1];
        adn = a_d[n];
    }
    float den = 0.f;
    float c[8] = {};
    int e = beg;
    while (__ballot(e < end) != 0ull) {
        const bool a0 = e < end, a1 = (e + 1) < end;
        const int i0 = a0 ? e : 0, i1 = a1 ? (e + 1) : 0;
        const int s0 = ssrc[i0], s1 = ssrc[i1];
        const float sc0 = a_s[s0], sc1 = a_s[s1];
        half8 v0 = *(const half8*)(xs + (size_t)s0 * OUT_CH + j8);
        half8 v1 = *(const half8*)(xs + (size_t)s1 * OUT_CH + j8);
        const float p0 = a0 ? __expf(lrelu(sc0 + adn)) : 0.f;
        const float p1 = a1 ? __expf(lrelu(sc1 + adn)) : 0.f;
        den += p0 + p1;
#pragma unroll
        for (int q = 0; q < 8; ++q)
            c[q] += p0 * (float)v0[q] + p1 * (float)v1[q];
        e += 2;
    }
    if (valid) {
        const float ps = __expf(lrelu(a_s[n] + adn));
        half8 sv = *(const half8*)(xs + (size_t)n * OUT_CH + j8);
        den += ps;
#pragma unroll
        for (int q = 0; q < 8; ++q) c[q] += ps * (float)sv[q];
        const float inv = 1.0f / den;
        float4 w0, w1;
        w0.x = c[0] * inv + bias[j8 + 0];
        w0.y = c[1] * inv + bias[j8 + 1];
        w0.z = c[2] * inv + bias[j8 + 2];
        w0.w = c[3] * inv + bias[j8 + 3];
        w1.x = c[4] * inv + bias[j8 + 4];
        w1.y = c[5] * inv + bias[j8 + 5];
        w1.z = c[6] * inv + bias[j8 + 6];
        w1.w = c[7] * inv + bias[j8 + 7];
        *(float4*)(out + (size_t)n * OUT_CH + j8)     = w0;
        *(float4*)(out + (size_t)n * OUT_CH + j8 + 4) = w1;
    }
}

// ---------------- launch ----------------

extern "C" void kernel_launch(void* const* d_in, const int* in_sizes, int n_in,
                              void* d_out, int out_size, void* d_ws, size_t ws_size,
                              hipStream_t stream) {
    const float* x     = (const float*)d_in[0];
    const int*   ei    = (const int*)d_in[1];      // int32 edge index [2, E]
    const float* W1    = (const float*)d_in[2];
    const float* atts1 = (const float*)d_in[3];
    const float* attd1 = (const float*)d_in[4];
    const float* bias1 = (const float*)d_in[5];
    const float* W2    = (const float*)d_in[6];
    const float* atts2 = (const float*)d_in[7];
    const float* attd2 = (const float*)d_in[8];
    const float* bias2 = (const float*)d_in[9];
    float*       out   = (float*)d_out;

    const int* srcp = ei;
    const int* dstp = ei + NE;

    char* ws = (char*)d_ws;
    size_t off = 0;
    auto alloc = [&](size_t bytes) -> void* {
        void* p = ws + off;
        off += (bytes + 255) & ~(size_t)255;
        return p;
    };
    _Float16* xh    = (_Float16*)alloc((size_t)NN * IN_CH * 2);  // 12.8 MB
    _Float16* xsh1  = (_Float16*)alloc((size_t)NN * HC * 2);     // 25.6 MB head-major
    _Float16* h1h   = (_Float16*)alloc((size_t)NN * HC * 2);     // 25.6 MB row-major
    _Float16* W1t   = (_Float16*)alloc((size_t)HC * IN_CH * 2);
    _Float16* W2t   = (_Float16*)alloc((size_t)OUT_CH * HC * 2);
    float*    as1   = (float*)alloc((size_t)NN * HEADS * 4);     // head-major [8][NN]
    float*    ad1   = (float*)alloc((size_t)NN * HEADS * 4);
    int*   deg      = (int*)alloc((size_t)NN * 4);
    int*   offsets  = (int*)alloc((size_t)(NN + 1) * 4);
    int*   cursor   = (int*)alloc((size_t)NN * 4);
    int*   ssrc     = (int*)alloc((size_t)NE * 4);
    int*   excl     = (int*)alloc((size_t)NN * 4);
    int*   bsum     = (int*)alloc((size_t)SCAN_BLOCKS * 4);
    int*   boff     = (int*)alloc((size_t)SCAN_BLOCKS * 4);
    // layer-2 scratch aliases layer-1 buffers dead after agg1:
    _Float16* xs2h = xsh1;
    float*    as2  = as1;
    float*    ad2  = ad1;

    // --- CSR build ---
    hipMemsetAsync(deg, 0, (size_t)NN * 4, stream);
    hist_kernel<<<(NE + 255) / 256, 256, 0, stream>>>(dstp, deg);
    scan_phase1<<<SCAN_BLOCKS, 256, 0, stream>>>(deg, excl, bsum);
    scan_phase2<<<1, 256, 0, stream>>>(bsum, boff, offsets);
    scan_phase3<<<SCAN_BLOCKS, 256, 0, stream>>>(excl, boff, offsets, cursor);
    scatter_kernel<<<(NE + 255) / 256, 256, 0, stream>>>(srcp, dstp, cursor, ssrc);

    // --- fp16 prep ---
    cast_f32_f16<<<(NN * IN_CH / 8 + 255) / 256, 256, 0, stream>>>(x, xh, NN * IN_CH / 8);
    transpose_cast<<<(IN_CH * HC + 255) / 256, 256, 0, stream>>>(W1, W1t, IN_CH, HC);
    transpose_cast<<<(HC * OUT_CH + 255) / 256, 256, 0, stream>>>(W2, W2t, HC, OUT_CH);

    // --- layer 1 ---
    {
        dim3 grid((NN + 63) / 64, HC / 64);
        gemm_mfma_hm<<<grid, 256, 0, stream>>>(xh, W1t, xsh1, NN, HC, IN_CH);
    }
    {
        dim3 grid((NN + 255) / 256, HEADS);
        attcoef1<<<grid, 256, 0, stream>>>(xsh1, atts1, attd1, as1, ad1);
    }
    agg1<<<((NN + 31) / 32) * 8, 256, 0, stream>>>(xsh1, as1, ad1, offsets, ssrc, bias1, h1h);

    // --- layer 2 ---
    {
        dim3 grid((NN + 63) / 64, OUT_CH / 64);
        gemm_mfma_h<<<grid, 256, 0, stream>>>(h1h, W2t, xs2h, NN, OUT_CH, HC);
    }
    attcoef2<<<(NN + 255) / 256, 256, 0, stream>>>(xs2h, atts2, attd2, as2, ad2);
    agg2<<<(NN + 31) / 32, 256, 0, stream>>>(xs2h, as2, ad2, offsets, ssrc, bias2, out);
}

// Round 11
// 325.849 us; speedup vs baseline: 1.2714x; 1.0004x over previous
//
#include <hip/hip_runtime.h>

#define NN 50000
#define NE 800000
#define IN_CH 128
#define HID 32
#define HEADS 8
#define HC 256          // HEADS*HID
#define OUT_CH 64
#define NEG_SLOPE 0.2f
#define SCAN_BLOCKS 196  // 196*256 = 50176 >= NN

typedef _Float16 half4 __attribute__((ext_vector_type(4)));
typedef _Float16 half8 __attribute__((ext_vector_type(8)));
typedef float    f32x4 __attribute__((ext_vector_type(4)));

// ---------------- counting sort (CSR by dst) ----------------

__global__ void hist_kernel(const int* __restrict__ dst, int* __restrict__ deg) {
    int e = blockIdx.x * blockDim.x + threadIdx.x;
    if (e < NE) atomicAdd(&deg[dst[e]], 1);
}

__global__ __launch_bounds__(256)
void scan_phase1(const int* __restrict__ deg, int* __restrict__ excl,
                 int* __restrict__ bsum) {
    __shared__ int sm[256];
    const int t = blockIdx.x * 256 + threadIdx.x;
    const int v = (t < NN) ? deg[t] : 0;
    sm[threadIdx.x] = v;
    __syncthreads();
    for (int off = 1; off < 256; off <<= 1) {
        int u = (threadIdx.x >= off) ? sm[threadIdx.x - off] : 0;
        __syncthreads();
        sm[threadIdx.x] += u;
        __syncthreads();
    }
    if (t < NN) excl[t] = sm[threadIdx.x] - v;
    if (threadIdx.x == 255) bsum[blockIdx.x] = sm[255];
}

__global__ __launch_bounds__(256)
void scan_phase2(const int* __restrict__ bsum, int* __restrict__ boff,
                 int* __restrict__ offsets) {
    __shared__ int sm[256];
    const int t = threadIdx.x;
    const int v = (t < SCAN_BLOCKS) ? bsum[t] : 0;
    sm[t] = v;
    __syncthreads();
    for (int off = 1; off < 256; off <<= 1) {
        int u = (t >= off) ? sm[t - off] : 0;
        __syncthreads();
        sm[t] += u;
        __syncthreads();
    }
    if (t < SCAN_BLOCKS) boff[t] = sm[t] - v;
    if (t == 255) offsets[NN] = sm[255];
}

__global__ __launch_bounds__(256)
void scan_phase3(const int* __restrict__ excl, const int* __restrict__ boff,
                 int* __restrict__ offsets, int* __restrict__ cursor) {
    const int t = blockIdx.x * 256 + threadIdx.x;
    if (t < NN) {
        int v = excl[t] + boff[blockIdx.x];
        offsets[t] = v;
        cursor[t]  = v;
    }
}

// also records dst per CSR slot (needed by edge-softmax precompute)
__global__ void scatter_kernel(const int* __restrict__ src,
                               const int* __restrict__ dst,
                               int* __restrict__ cursor, int* __restrict__ ssrc,
                               int* __restrict__ sdst) {
    int e = blockIdx.x * blockDim.x + threadIdx.x;
    if (e < NE) {
        int d = dst[e];
        int pos = atomicAdd(&cursor[d], 1);
        ssrc[pos] = src[e];
        sdst[pos] = d;
    }
}

// ---------------- fp16 prep ----------------

__global__ void cast_f32_f16(const float* __restrict__ in, _Float16* __restrict__ out,
                             int n8) {
    int i = blockIdx.x * blockDim.x + threadIdx.x;
    if (i >= n8) return;
    float4 a = ((const float4*)in)[i * 2];
    float4 b = ((const float4*)in)[i * 2 + 1];
    half8 h;
    h[0] = (_Float16)a.x; h[1] = (_Float16)a.y; h[2] = (_Float16)a.z; h[3] = (_Float16)a.w;
    h[4] = (_Float16)b.x; h[5] = (_Float16)b.y; h[6] = (_Float16)b.z; h[7] = (_Float16)b.w;
    ((half8*)out)[i] = h;
}

// Wt[n][k] = (fp16) W[k][n]
__global__ void transpose_cast(const float* __restrict__ W, _Float16* __restrict__ Wt,
                               int K, int N) {
    int i = blockIdx.x * blockDim.x + threadIdx.x;
    if (i >= K * N) return;
    int k = i / N, n = i - k * N;
    Wt[(size_t)n * K + k] = (_Float16)W[i];
}

// ---------------- MFMA fp16 GEMM (row-major C) ----------------
__global__ __launch_bounds__(256)
void gemm_mfma_h(const _Float16* __restrict__ A, const _Float16* __restrict__ Bt,
                 _Float16* __restrict__ C, int M, int N, int K) {
    __shared__ _Float16 Asl[64][136];
    __shared__ _Float16 Btl[64][136];
    const int tid  = threadIdx.x;
    const int wave = tid >> 6, lane = tid & 63;
    const int lr = lane & 15, lk = lane >> 4;
    const int bm = blockIdx.x * 64, bn = blockIdx.y * 64;
    const int sr = tid >> 2;
    const int ss = (tid & 3) * 32;

    f32x4 acc[4];
#pragma unroll
    for (int i = 0; i < 4; ++i) acc[i] = (f32x4){0.f, 0.f, 0.f, 0.f};

    for (int k0 = 0; k0 < K; k0 += 128) {
        {
            const int ar = bm + sr;
            half8 v0 = {}, v1 = {}, v2 = {}, v3 = {};
            if (ar < M) {
                const half8* ga = (const half8*)(A + (size_t)ar * K + k0 + ss);
                v0 = ga[0]; v1 = ga[1]; v2 = ga[2]; v3 = ga[3];
            }
            *(half8*)&Asl[sr][ss + 0]  = v0;
            *(half8*)&Asl[sr][ss + 8]  = v1;
            *(half8*)&Asl[sr][ss + 16] = v2;
            *(half8*)&Asl[sr][ss + 24] = v3;
            const half8* gb = (const half8*)(Bt + (size_t)(bn + sr) * K + k0 + ss);
            half8 w0 = gb[0], w1 = gb[1], w2 = gb[2], w3 = gb[3];
            *(half8*)&Btl[sr][ss + 0]  = w0;
            *(half8*)&Btl[sr][ss + 8]  = w1;
            *(half8*)&Btl[sr][ss + 16] = w2;
            *(half8*)&Btl[sr][ss + 24] = w3;
        }
        __syncthreads();
#pragma unroll
        for (int kk = 0; kk < 128; kk += 32) {
            half8 a = *(const half8*)&Asl[wave * 16 + lr][kk + lk * 8];
#pragma unroll
            for (int nt = 0; nt < 4; ++nt) {
                half8 b = *(const half8*)&Btl[nt * 16 + lr][kk + lk * 8];
                acc[nt] = __builtin_amdgcn_mfma_f32_16x16x32_f16(a, b, acc[nt], 0, 0, 0);
            }
        }
        __syncthreads();
    }
#pragma unroll
    for (int nt = 0; nt < 4; ++nt) {
        const int col = bn + nt * 16 + lr;
#pragma unroll
        for (int r = 0; r < 4; ++r) {
            const int m = bm + wave * 16 + lk * 4 + r;
            if (m < M) C[(size_t)m * N + col] = (_Float16)acc[nt][r];
        }
    }
}

// ---------------- MFMA fp16 GEMM (head-major C: [N/32][M][32]) ----------------
__global__ __launch_bounds__(256)
void gemm_mfma_hm(const _Float16* __restrict__ A, const _Float16* __restrict__ Bt,
                  _Float16* __restrict__ C, int M, int N, int K) {
    __shared__ _Float16 Asl[64][136];
    __shared__ _Float16 Btl[64][136];
    const int tid  = threadIdx.x;
    const int wave = tid >> 6, lane = tid & 63;
    const int lr = lane & 15, lk = lane >> 4;
    const int bm = blockIdx.x * 64, bn = blockIdx.y * 64;
    const int sr = tid >> 2;
    const int ss = (tid & 3) * 32;

    f32x4 acc[4];
#pragma unroll
    for (int i = 0; i < 4; ++i) acc[i] = (f32x4){0.f, 0.f, 0.f, 0.f};

    for (int k0 = 0; k0 < K; k0 += 128) {
        {
            const int ar = bm + sr;
            half8 v0 = {}, v1 = {}, v2 = {}, v3 = {};
            if (ar < M) {
                const half8* ga = (const half8*)(A + (size_t)ar * K + k0 + ss);
                v0 = ga[0]; v1 = ga[1]; v2 = ga[2]; v3 = ga[3];
            }
            *(half8*)&Asl[sr][ss + 0]  = v0;
            *(half8*)&Asl[sr][ss + 8]  = v1;
            *(half8*)&Asl[sr][ss + 16] = v2;
            *(half8*)&Asl[sr][ss + 24] = v3;
            const half8* gb = (const half8*)(Bt + (size_t)(bn + sr) * K + k0 + ss);
            half8 w0 = gb[0], w1 = gb[1], w2 = gb[2], w3 = gb[3];
            *(half8*)&Btl[sr][ss + 0]  = w0;
            *(half8*)&Btl[sr][ss + 8]  = w1;
            *(half8*)&Btl[sr][ss + 16] = w2;
            *(half8*)&Btl[sr][ss + 24] = w3;
        }
        __syncthreads();
#pragma unroll
        for (int kk = 0; kk < 128; kk += 32) {
            half8 a = *(const half8*)&Asl[wave * 16 + lr][kk + lk * 8];
#pragma unroll
            for (int nt = 0; nt < 4; ++nt) {
                half8 b = *(const half8*)&Btl[nt * 16 + lr][kk + lk * 8];
                acc[nt] = __builtin_amdgcn_mfma_f32_16x16x32_f16(a, b, acc[nt], 0, 0, 0);
            }
        }
        __syncthreads();
    }
#pragma unroll
    for (int nt = 0; nt < 4; ++nt) {
        const int col = bn + nt * 16 + lr;
        const int hh = col >> 5, cc = col & 31;
#pragma unroll
        for (int r = 0; r < 4; ++r) {
            const int m = bm + wave * 16 + lk * 4 + r;
            if (m < M) C[((size_t)hh * M + m) * 32 + cc] = (_Float16)acc[nt][r];
        }
    }
}

// ---------------- attention coefficients ----------------

__device__ __forceinline__ float lrelu(float x) { return x > 0.f ? x : NEG_SLOPE * x; }

// layer 1: writes node-major asn/adn2 (for pedge1 gathers) + self numerators.
__global__ void attcoef1(const _Float16* __restrict__ xsh, const float* __restrict__ att_s,
                         const float* __restrict__ att_d,
                         float* __restrict__ asn,      // [NN][8]
                         float* __restrict__ adn2,     // [NN][8]
                         float* __restrict__ pself1) { // [8][NN]
    int n = blockIdx.x * blockDim.x + threadIdx.x;
    int h = blockIdx.y;
    if (n >= NN) return;
    const _Float16* xp = xsh + ((size_t)h * NN + n) * 32;
    const float* sp = att_s + h * 32;
    const float* dp = att_d + h * 32;
    float as = 0.f, ad = 0.f;
#pragma unroll
    for (int i = 0; i < 4; ++i) {
        half8 v = *(const half8*)(xp + i * 8);
#pragma unroll
        for (int j = 0; j < 8; ++j) {
            float f = (float)v[j];
            as += f * sp[i * 8 + j];
            ad += f * dp[i * 8 + j];
        }
    }
    asn[(size_t)n * 8 + h]  = as;
    adn2[(size_t)n * 8 + h] = ad;
    pself1[(size_t)h * NN + n] = __expf(lrelu(as + ad));
}

// layer 1 edge numerators: p1[h][i] = exp(lrelu(asn[s][h] + adn2[d][h]))
__global__ void pedge1(const int* __restrict__ ssrc, const int* __restrict__ sdst,
                       const float* __restrict__ asn, const float* __restrict__ adn2,
                       float* __restrict__ p1) {
    int i = blockIdx.x * blockDim.x + threadIdx.x;
    if (i >= NE) return;
    int s = ssrc[i], d = sdst[i];
    float4 A0 = *(const float4*)(asn + (size_t)s * 8);
    float4 A1 = *(const float4*)(asn + (size_t)s * 8 + 4);
    float4 D0 = *(const float4*)(adn2 + (size_t)d * 8);
    float4 D1 = *(const float4*)(adn2 + (size_t)d * 8 + 4);
    p1[0 * NE + i] = __expf(lrelu(A0.x + D0.x));
    p1[1 * NE + i] = __expf(lrelu(A0.y + D0.y));
    p1[2 * NE + i] = __expf(lrelu(A0.z + D0.z));
    p1[3 * NE + i] = __expf(lrelu(A0.w + D0.w));
    p1[4 * NE + i] = __expf(lrelu(A1.x + D1.x));
    p1[5 * NE + i] = __expf(lrelu(A1.y + D1.y));
    p1[6 * NE + i] = __expf(lrelu(A1.z + D1.z));
    p1[7 * NE + i] = __expf(lrelu(A1.w + D1.w));
}

__global__ void attcoef2(const _Float16* __restrict__ xs, const float* __restrict__ att_s,
                         const float* __restrict__ att_d,
                         float* __restrict__ a_s, float* __restrict__ a_d,
                         float* __restrict__ pself2) {
    int n = blockIdx.x * blockDim.x + threadIdx.x;
    if (n >= NN) return;
    const _Float16* xp = xs + (long)n * 64;
    float as = 0.f, ad = 0.f;
#pragma unroll
    for (int i = 0; i < 8; ++i) {
        half8 v = *(const half8*)(xp + i * 8);
#pragma unroll
        for (int j = 0; j < 8; ++j) {
            float f = (float)v[j];
            as += f * att_s[i * 8 + j];
            ad += f * att_d[i * 8 + j];
        }
    }
    a_s[n] = as;
    a_d[n] = ad;
    pself2[n] = __expf(lrelu(as + ad));
}

__global__ void pedge2(const int* __restrict__ ssrc, const int* __restrict__ sdst,
                       const float* __restrict__ a_s, const float* __restrict__ a_d,
                       float* __restrict__ p2) {
    int i = blockIdx.x * blockDim.x + threadIdx.x;
    if (i >= NE) return;
    p2[i] = __expf(lrelu(a_s[ssrc[i]] + a_d[sdst[i]]));
}

// ---------------- aggregation (pure gather+FMA; numerators precomputed) ----------------

// layer 1: wave = (head, 8 node-slots x 8 lanes); head=blockIdx&7 keeps the
// per-head 3.2MB table XCD/L2-resident (r9: FETCH 221->45MB). Inner loop has
// no exp/lrelu/score-gather (r10: VALUBusy 70% -> hoisted to pedge1).
__global__ __launch_bounds__(256)
void agg1(const _Float16* __restrict__ xsh,   // [8][NN][32]
          const float* __restrict__ p1,       // [8][NE]
          const float* __restrict__ pself1,   // [8][NN]
          const int* __restrict__ offsets, const int* __restrict__ ssrc,
          const float* __restrict__ bias,
          _Float16* __restrict__ out) {       // [NN][256]
    const int head = blockIdx.x & 7;
    const int grp  = blockIdx.x >> 3;
    const int wave = threadIdx.x >> 6;
    const int lane = threadIdx.x & 63;
    const int slot = lane >> 3;
    const int j4   = (lane & 7) * 4;
    const int n    = grp * 32 + wave * 8 + slot;
    const bool valid = (n < NN);
    const _Float16* xh = xsh + (size_t)head * NN * 32;
    const float* pe = p1 + (size_t)head * NE;

    int beg = 0, end = 0;
    if (valid) { beg = offsets[n]; end = offsets[n + 1]; }
    float den = 0.f, c0 = 0.f, c1 = 0.f, c2 = 0.f, c3 = 0.f;
    int e = beg;
    while (__ballot(e < end) != 0ull) {
        const bool a0 = e < end, a1 = e + 1 < end, a2 = e + 2 < end, a3 = e + 3 < end;
        const int s0 = ssrc[a0 ? e : 0],     s1 = ssrc[a1 ? e + 1 : 0];
        const int s2 = ssrc[a2 ? e + 2 : 0], s3 = ssrc[a3 ? e + 3 : 0];
        const float q0 = a0 ? pe[e] : 0.f,     q1 = a1 ? pe[e + 1] : 0.f;
        const float q2 = a2 ? pe[e + 2] : 0.f, q3 = a3 ? pe[e + 3] : 0.f;
        half4 v0 = *(const half4*)(xh + (size_t)s0 * 32 + j4);
        half4 v1 = *(const half4*)(xh + (size_t)s1 * 32 + j4);
        half4 v2 = *(const half4*)(xh + (size_t)s2 * 32 + j4);
        half4 v3 = *(const half4*)(xh + (size_t)s3 * 32 + j4);
        den += (q0 + q1) + (q2 + q3);
        c0 += q0 * (float)v0[0] + q1 * (float)v1[0] + q2 * (float)v2[0] + q3 * (float)v3[0];
        c1 += q0 * (float)v0[1] + q1 * (float)v1[1] + q2 * (float)v2[1] + q3 * (float)v3[1];
        c2 += q0 * (float)v0[2] + q1 * (float)v1[2] + q2 * (float)v2[2] + q3 * (float)v3[2];
        c3 += q0 * (float)v0[3] + q1 * (float)v1[3] + q2 * (float)v2[3] + q3 * (float)v3[3];
        e += 4;
    }
    if (valid) {
        const float ps = pself1[(size_t)head * NN + n];
        half4 sv = *(const half4*)(xh + (size_t)n * 32 + j4);
        den += ps;
        c0 += ps * (float)sv[0]; c1 += ps * (float)sv[1];
        c2 += ps * (float)sv[2]; c3 += ps * (float)sv[3];
        const float inv = 1.0f / den;
        float4 bb = *(const float4*)(bias + head * 32 + j4);
        float o0 = c0 * inv + bb.x, o1 = c1 * inv + bb.y;
        float o2 = c2 * inv + bb.z, o3 = c3 * inv + bb.w;
        o0 = o0 > 0.f ? o0 : expm1f(o0);
        o1 = o1 > 0.f ? o1 : expm1f(o1);
        o2 = o2 > 0.f ? o2 : expm1f(o2);
        o3 = o3 > 0.f ? o3 : expm1f(o3);
        half4 ho;
        ho[0] = (_Float16)o0; ho[1] = (_Float16)o1;
        ho[2] = (_Float16)o2; ho[3] = (_Float16)o3;
        *(half4*)(out + (size_t)n * HC + head * 32 + j4) = ho;
    }
}

// layer 2: slot structure, H=1, C=64: 8 lanes x half8 = 128B row.
__global__ __launch_bounds__(256)
void agg2(const _Float16* __restrict__ xs,    // [NN][64]
          const float* __restrict__ p2,       // [NE]
          const float* __restrict__ pself2,   // [NN]
          const int* __restrict__ offsets, const int* __restrict__ ssrc,
          const float* __restrict__ bias,
          float* __restrict__ out) {          // [NN][64]
    const int grp  = blockIdx.x;
    const int wave = threadIdx.x >> 6;
    const int lane = threadIdx.x & 63;
    const int slot = lane >> 3;
    const int j8   = (lane & 7) * 8;
    const int n    = grp * 32 + wave * 8 + slot;
    const bool valid = (n < NN);

    int beg = 0, end = 0;
    if (valid) { beg = offsets[n]; end = offsets[n + 1]; }
    float den = 0.f;
    float c[8] = {};
    int e = beg;
    while (__ballot(e < end) != 0ull) {
        const bool a0 = e < end, a1 = e + 1 < end;
        const int s0 = ssrc[a0 ? e : 0], s1 = ssrc[a1 ? e + 1 : 0];
        const float q0 = a0 ? p2[e] : 0.f, q1 = a1 ? p2[e + 1] : 0.f;
        half8 v0 = *(const half8*)(xs + (size_t)s0 * OUT_CH + j8);
        half8 v1 = *(const half8*)(xs + (size_t)s1 * OUT_CH + j8);
        den += q0 + q1;
#pragma unroll
        for (int q = 0; q < 8; ++q)
            c[q] += q0 * (float)v0[q] + q1 * (float)v1[q];
        e += 2;
    }
    if (valid) {
        const float ps = pself2[n];
        half8 sv = *(const half8*)(xs + (size_t)n * OUT_CH + j8);
        den += ps;
#pragma unroll
        for (int q = 0; q < 8; ++q) c[q] += ps * (float)sv[q];
        const float inv = 1.0f / den;
        float4 w0, w1;
        w0.x = c[0] * inv + bias[j8 + 0];
        w0.y = c[1] * inv + bias[j8 + 1];
        w0.z = c[2] * inv + bias[j8 + 2];
        w0.w = c[3] * inv + bias[j8 + 3];
        w1.x = c[4] * inv + bias[j8 + 4];
        w1.y = c[5] * inv + bias[j8 + 5];
        w1.z = c[6] * inv + bias[j8 + 6];
        w1.w = c[7] * inv + bias[j8 + 7];
        *(float4*)(out + (size_t)n * OUT_CH + j8)     = w0;
        *(float4*)(out + (size_t)n * OUT_CH + j8 + 4) = w1;
    }
}

// ---------------- launch ----------------

extern "C" void kernel_launch(void* const* d_in, const int* in_sizes, int n_in,
                              void* d_out, int out_size, void* d_ws, size_t ws_size,
                              hipStream_t stream) {
    const float* x     = (const float*)d_in[0];
    const int*   ei    = (const int*)d_in[1];      // int32 edge index [2, E]
    const float* W1    = (const float*)d_in[2];
    const float* atts1 = (const float*)d_in[3];
    const float* attd1 = (const float*)d_in[4];
    const float* bias1 = (const float*)d_in[5];
    const float* W2    = (const float*)d_in[6];
    const float* atts2 = (const float*)d_in[7];
    const float* attd2 = (const float*)d_in[8];
    const float* bias2 = (const float*)d_in[9];
    float*       out   = (float*)d_out;

    const int* srcp = ei;
    const int* dstp = ei + NE;

    char* ws = (char*)d_ws;
    size_t off = 0;
    auto alloc = [&](size_t bytes) -> void* {
        void* p = ws + off;
        off += (bytes + 255) & ~(size_t)255;
        return p;
    };
    _Float16* xh     = (_Float16*)alloc((size_t)NN * IN_CH * 2);   // 12.8 MB
    _Float16* xsh1   = (_Float16*)alloc((size_t)NN * HC * 2);      // 25.6 MB head-major
    _Float16* h1h    = (_Float16*)alloc((size_t)NN * HC * 2);      // 25.6 MB row-major
    float*    p1     = (float*)alloc((size_t)HEADS * NE * 4);      // 25.6 MB
    _Float16* W1t    = (_Float16*)alloc((size_t)HC * IN_CH * 2);
    _Float16* W2t    = (_Float16*)alloc((size_t)OUT_CH * HC * 2);
    float*    asn    = (float*)alloc((size_t)NN * 8 * 4);          // 1.6 MB
    float*    adn2   = (float*)alloc((size_t)NN * 8 * 4);          // 1.6 MB
    float*    pself1 = (float*)alloc((size_t)HEADS * NN * 4);      // 1.6 MB
    float*    as2    = (float*)alloc((size_t)NN * 4);
    float*    ad2    = (float*)alloc((size_t)NN * 4);
    float*    pself2 = (float*)alloc((size_t)NN * 4);
    float*    p2     = (float*)alloc((size_t)NE * 4);              // 3.2 MB
    int*   deg      = (int*)alloc((size_t)NN * 4);
    int*   offsets  = (int*)alloc((size_t)(NN + 1) * 4);
    int*   cursor   = (int*)alloc((size_t)NN * 4);
    int*   ssrc     = (int*)alloc((size_t)NE * 4);                 // 3.2 MB
    int*   sdst     = (int*)alloc((size_t)NE * 4);                 // 3.2 MB
    int*   excl     = (int*)alloc((size_t)NN * 4);
    int*   bsum     = (int*)alloc((size_t)SCAN_BLOCKS * 4);
    int*   boff     = (int*)alloc((size_t)SCAN_BLOCKS * 4);
    _Float16* xs2h = xsh1;   // layer-2 features alias (dead after agg1)

    // --- CSR build ---
    hipMemsetAsync(deg, 0, (size_t)NN * 4, stream);
    hist_kernel<<<(NE + 255) / 256, 256, 0, stream>>>(dstp, deg);
    scan_phase1<<<SCAN_BLOCKS, 256, 0, stream>>>(deg, excl, bsum);
    scan_phase2<<<1, 256, 0, stream>>>(bsum, boff, offsets);
    scan_phase3<<<SCAN_BLOCKS, 256, 0, stream>>>(excl, boff, offsets, cursor);
    scatter_kernel<<<(NE + 255) / 256, 256, 0, stream>>>(srcp, dstp, cursor, ssrc, sdst);

    // --- fp16 prep ---
    cast_f32_f16<<<(NN * IN_CH / 8 + 255) / 256, 256, 0, stream>>>(x, xh, NN * IN_CH / 8);
    transpose_cast<<<(IN_CH * HC + 255) / 256, 256, 0, stream>>>(W1, W1t, IN_CH, HC);
    transpose_cast<<<(HC * OUT_CH + 255) / 256, 256, 0, stream>>>(W2, W2t, HC, OUT_CH);

    // --- layer 1 ---
    {
        dim3 grid((NN + 63) / 64, HC / 64);
        gemm_mfma_hm<<<grid, 256, 0, stream>>>(xh, W1t, xsh1, NN, HC, IN_CH);
    }
    {
        dim3 grid((NN + 255) / 256, HEADS);
        attcoef1<<<grid, 256, 0, stream>>>(xsh1, atts1, attd1, asn, adn2, pself1);
    }
    pedge1<<<(NE + 255) / 256, 256, 0, stream>>>(ssrc, sdst, asn, adn2, p1);
    agg1<<<((NN + 31) / 32) * 8, 256, 0, stream>>>(xsh1, p1, pself1, offsets, ssrc, bias1, h1h);

    // --- layer 2 ---
    {
        dim3 grid((NN + 63) / 64, OUT_CH / 64);
        gemm_mfma_h<<<grid, 256, 0, stream>>>(h1h, W2t, xs2h, NN, OUT_CH, HC);
    }
    attcoef2<<<(NN + 255) / 256, 256, 0, stream>>>(xs2h, atts2, attd2, as2, ad2, pself2);
    pedge2<<<(NE + 255) / 256, 256, 0, stream>>>(ssrc, sdst, as2, ad2, p2);
    agg2<<<(NN + 31) / 32, 256, 0, stream>>>(xs2h, p2, pself2, offsets, ssrc, bias2, out);
}